// Round 14
// baseline (43.456 us; speedup 1.0000x reference)
//
#include <hip/hip_runtime.h>
#include <hip/hip_fp16.h>

// O = U X U^H, U = kron of 11 single-qubit SU(2) gates (2048^2 complex64).
// Reordered as O = U * (X * U^H). Two kernels:
//   K1 rowwaveK1: Y = X U^H (row transform, conj gates). THIS ROUND:
//      wave-per-row, NO LDS, NO barriers. Lane l holds j = l + 64m
//      (32 v2f in registers). j bits 0-5 = lane bits -> 6 shfl_xor
//      butterfly stages (own/partner coefs hoisted per stage, no
//      per-element selects); j bits 6-10 -> 5 in-register stages.
//      Pure streaming kernel. Y fp16 COLUMN-BLOCKED [jblk][row][jin].
//   K2 colfused: full 11-stage column transform, 8-col strip per block,
//      1024 thr, 16 elems/thread, 3 phases, packed half2 LDS (72 KB),
//      XCD-aware strip swizzle. (round-13 verbatim, passed)
// Butterflies: VOP3P packed fp32 (v_pk_fma_f32 + op_sel Re/Im swap, signs
// baked into gate constants). Traffic ~64 MB.

#define DIM 2048
#define NQ 11

typedef float v2f __attribute__((ext_vector_type(2)));

__device__ __forceinline__ float2 cmul(float2 a, float2 b) {
    return make_float2(a.x * b.x - a.y * b.y, a.x * b.y + a.y * b.x);
}

// ---- VOP3P packed helpers -------------------------------------------------
__device__ __forceinline__ v2f pkmul_swap(v2f s, v2f g) {
    v2f d;
    asm("v_pk_mul_f32 %0, %1, %2 op_sel:[1,0] op_sel_hi:[0,1]"
        : "=v"(d) : "v"(s), "v"(g));
    return d;
}
__device__ __forceinline__ v2f pkfma(v2f s0, v2f s1, v2f c) {
    v2f d;
    asm("v_pk_fma_f32 %0, %1, %2, %3" : "=v"(d) : "v"(s0), "v"(s1), "v"(c));
    return d;
}
__device__ __forceinline__ v2f pkfma_swap(v2f s0, v2f s1, v2f c) {
    v2f d;
    asm("v_pk_fma_f32 %0, %1, %2, %3 op_sel:[1,0,0] op_sel_hi:[0,1,1]"
        : "=v"(d) : "v"(s0), "v"(s1), "v"(c));
    return d;
}

struct PkGate {
    v2f x00, y00, x01, y01, x10, y10, x11, y11;
};

// Composite gate g = Rz @ Ry @ Rx for qubit q; conj!=0 -> conjugate entries.
__device__ __forceinline__ void make_gate(const float* __restrict__ w, int q,
                                          int conj, float2* out4) {
    const float WM = 0.632455532033675866f;  // sqrt(2/5)
    float hx = 0.5f * WM * w[q * 3 + 0];
    float hy = 0.5f * WM * w[q * 3 + 1];
    float hz = 0.5f * WM * w[q * 3 + 2];
    float cx, sx, cy, sy, cz, sz;
    sincosf(hx, &sx, &cx);
    sincosf(hy, &sy, &cy);
    sincosf(hz, &sz, &cz);
    float2 m00 = make_float2(cy * cx,  sy * sx);
    float2 m01 = make_float2(-sy * cx, -cy * sx);
    float2 m10 = make_float2(sy * cx,  -cy * sx);
    float2 m11 = make_float2(cy * cx,  -sy * sx);
    float2 ez  = make_float2(cz, -sz);
    float2 ezc = make_float2(cz,  sz);
    float2 g00 = cmul(ez, m00);
    float2 g01 = cmul(ez, m01);
    float2 g10 = cmul(ezc, m10);
    float2 g11 = cmul(ezc, m11);
    float sgn = conj ? -1.f : 1.f;
    out4[0] = make_float2(g00.x, sgn * g00.y);
    out4[1] = make_float2(g01.x, sgn * g01.y);
    out4[2] = make_float2(g10.x, sgn * g10.y);
    out4[3] = make_float2(g11.x, sgn * g11.y);
}

__device__ __forceinline__ void build_pk_gates(const float* __restrict__ wt,
                                               int t, int conj,
                                               v2f (*gsh)[8]) {
    if (t < NQ) {
        float2 e[4];
        make_gate(wt, t, conj, e);
#pragma unroll
        for (int k = 0; k < 4; ++k) {
            v2f px = {e[k].x, e[k].x};
            v2f py = {-e[k].y, e[k].y};
            gsh[t][2 * k + 0] = px;
            gsh[t][2 * k + 1] = py;
        }
    }
}

__device__ __forceinline__ void load_pkgate(const v2f (*gsh)[8], int q,
                                            PkGate& G) {
    G.x00 = gsh[q][0]; G.y00 = gsh[q][1];
    G.x01 = gsh[q][2]; G.y01 = gsh[q][3];
    G.x10 = gsh[q][4]; G.y10 = gsh[q][5];
    G.x11 = gsh[q][6]; G.y11 = gsh[q][7];
}

// Butterfly: (A,B) <- (E00 A + E01 B, E10 A + E11 B), 8 VOP3P instrs.
__device__ __forceinline__ void bfly(float2& A, float2& B, const PkGate& G) {
    v2f a = __builtin_bit_cast(v2f, A), b = __builtin_bit_cast(v2f, B);
    v2f t;
    t = pkmul_swap(b, G.y01);
    t = pkfma(b, G.x01, t);
    t = pkfma_swap(a, G.y00, t);
    A = __builtin_bit_cast(float2, pkfma(a, G.x00, t));
    t = pkmul_swap(b, G.y11);
    t = pkfma(b, G.x11, t);
    t = pkfma_swap(a, G.y10, t);
    B = __builtin_bit_cast(float2, pkfma(a, G.x10, t));
}

template <int ST>
__device__ __forceinline__ void stage16(float2* v, const PkGate& G) {
#pragma unroll
    for (int m = 0; m < 16; ++m)
        if (!(m & ST)) bfly(v[m], v[m + ST], G);
}

template <int ST>
__device__ __forceinline__ void stage32(float2* v, const PkGate& G) {
#pragma unroll
    for (int m = 0; m < 32; ++m)
        if (!(m & ST)) bfly(v[m], v[m + ST], G);
}

__device__ __forceinline__ unsigned pack_h2(float2 v) {
    __half2 h = __float22half2_rn(v);
    return *reinterpret_cast<unsigned*>(&h);
}
__device__ __forceinline__ float2 unpack_h2(unsigned u) {
    __half2 h = *reinterpret_cast<__half2*>(&u);
    return __half22float2(h);
}

// ---------------- K1: Y = X U^H, wave-per-row, no LDS ----------------------
// Lane l holds j = l + 64m, m = 0..31. j bit b (b<6) -> shfl_xor(1<<b)
// stage with gates of qubit 10-b; j bit 6+k -> in-register stride 1<<k
// stage with gates of qubit 4-k.
// Y layout: column-blocked fp16, Y[jblk][row][jin], jblk=j>>3, jin=j&7.
__global__ __launch_bounds__(256, 2) void rowwaveK1(
    const float* __restrict__ X, unsigned* __restrict__ Y,
    const float* __restrict__ wt) {
    __shared__ v2f gsh[NQ][8];
    int t = threadIdx.x;
    build_pk_gates(wt, t, 1, gsh);      // conjugated gates
    __syncthreads();                     // once; no barriers after this

    int l = t & 63;
    int row = blockIdx.x * 4 + (t >> 6);
    const float* xrow = X + (size_t)row * DIM;

    // Load: lane l takes j = l + 64m (coalesced 256B/wave per m). X real.
    float2 v[32];
#pragma unroll
    for (int m = 0; m < 32; ++m)
        v[m] = make_float2(xrow[l + (m << 6)], 0.f);

    // 6 shfl stages: j bits 0..5 -> qubits 10..5.
#pragma unroll
    for (int b = 0; b < 6; ++b) {
        PkGate G;
        load_pkgate(gsh, 10 - b, G);
        bool hi = (l >> b) & 1;
        v2f s0x = hi ? G.x11 : G.x00, s0y = hi ? G.y11 : G.y00;  // own coef
        v2f s1x = hi ? G.x10 : G.x01, s1y = hi ? G.y10 : G.y01;  // partner
#pragma unroll
        for (int m = 0; m < 32; ++m) {
            v2f pv;
            pv[0] = __shfl_xor(v[m].x, 1 << b);
            pv[1] = __shfl_xor(v[m].y, 1 << b);
            v2f a = __builtin_bit_cast(v2f, v[m]);
            v2f tt = pkmul_swap(pv, s1y);
            tt = pkfma(pv, s1x, tt);
            tt = pkfma_swap(a, s0y, tt);
            v[m] = __builtin_bit_cast(float2, pkfma(a, s0x, tt));
        }
    }

    // 5 in-register stages: j bit 6+k (m-stride 1<<k) -> qubit 4-k.
    PkGate G;
    load_pkgate(gsh, 4, G); stage32<1>(v, G);
    load_pkgate(gsh, 3, G); stage32<2>(v, G);
    load_pkgate(gsh, 2, G); stage32<4>(v, G);
    load_pkgate(gsh, 1, G); stage32<8>(v, G);
    load_pkgate(gsh, 0, G); stage32<16>(v, G);

    // Store fp16 column-blocked: j = l+64m -> jblk = (l>>3)+8m, jin = l&7.
    unsigned* yp = Y + (size_t)(l >> 3) * (DIM * 8) + (size_t)row * 8 + (l & 7);
#pragma unroll
    for (int m = 0; m < 32; ++m)
        yp[(size_t)m * 8 * (DIM * 8)] = pack_h2(v[m]);
}

// -------- K2: full column transform (row bits 0-10), 8-col strip -----------
// 1024 threads, 16 elems/thread. Phases: A bits 7-10 | M bits 3-6 | F 0-2.
// LDS: packed half2 (u32), word = r*9 + c (pad-9, <=4-way banks). 72 KB ->
// 2 resident blocks/CU. XCD-aware strip swizzle. (round-13 verbatim)
__global__ __launch_bounds__(1024, 4) void colfused(
    const unsigned* __restrict__ Y, float* __restrict__ Out,
    const float* __restrict__ wt, int writeComplex) {
    __shared__ unsigned pk[DIM * 9];
    __shared__ v2f gsh[NQ][8];
    int t = threadIdx.x;
    build_pk_gates(wt, t, 0, gsh);
    __syncthreads();

    // XCD swizzle (8 XCDs, 256 blocks): strips 32k..32k+31 share XCD k.
    int strip = ((blockIdx.x & 7) << 5) + (blockIdx.x >> 3);

    int c = t & 7, u = t >> 3;          // u in 0..127
    const unsigned* yb = Y + (size_t)strip * (DIM * 8);

    // Phase A: r = u + 128m (bits 7-10 -> qubits 3,2,1,0).
    float2 v[16];
    PkGate G;
#pragma unroll
    for (int m = 0; m < 16; ++m)
        v[m] = unpack_h2(yb[(u + (m << 7)) * 8 + c]);

    load_pkgate(gsh, 3, G); stage16<1>(v, G);   // bit 7
    load_pkgate(gsh, 2, G); stage16<2>(v, G);   // bit 8
    load_pkgate(gsh, 1, G); stage16<4>(v, G);   // bit 9
    load_pkgate(gsh, 0, G); stage16<8>(v, G);   // bit 10

#pragma unroll
    for (int m = 0; m < 16; ++m)
        pk[(u + (m << 7)) * 9 + c] = pack_h2(v[m]);
    __syncthreads();

    // Phase M: r = (u&7) + 8m + 128*(u>>3) (bits 3-6 -> qubits 7,6,5,4).
    int uLo = u & 7, uHi = u >> 3;
#pragma unroll
    for (int m = 0; m < 16; ++m)
        v[m] = unpack_h2(pk[(uLo + (m << 3) + (uHi << 7)) * 9 + c]);
    load_pkgate(gsh, 7, G); stage16<1>(v, G);
    load_pkgate(gsh, 6, G); stage16<2>(v, G);
    load_pkgate(gsh, 5, G); stage16<4>(v, G);
    load_pkgate(gsh, 4, G); stage16<8>(v, G);
#pragma unroll
    for (int m = 0; m < 16; ++m)
        pk[(uLo + (m << 3) + (uHi << 7)) * 9 + c] = pack_h2(v[m]);
    __syncthreads();

    // Phase F: r = m + 16u (bits 0-2 -> qubits 10,9,8).
#pragma unroll
    for (int m = 0; m < 16; ++m)
        v[m] = unpack_h2(pk[(m + (u << 4)) * 9 + c]);
    load_pkgate(gsh, 10, G); stage16<1>(v, G);
    load_pkgate(gsh, 9, G);  stage16<2>(v, G);
    load_pkgate(gsh, 8, G);  stage16<4>(v, G);

    // Write: thread holds rows r = 16u..16u+15 of column j = strip*8 + c.
    int j = strip * 8 + c;
    if (!writeComplex) {
#pragma unroll
        for (int m = 0; m < 16; ++m)
            Out[(size_t)(m + (u << 4)) * DIM + j] = v[m].x;
    } else {
        float2* o2 = (float2*)Out;
#pragma unroll
        for (int m = 0; m < 16; ++m)
            o2[(size_t)(m + (u << 4)) * DIM + j] = v[m];
    }
}

extern "C" void kernel_launch(void* const* d_in, const int* in_sizes, int n_in,
                              void* d_out, int out_size, void* d_ws,
                              size_t ws_size, hipStream_t stream) {
    const float* X = (const float*)d_in[0];
    const float* wt = (const float*)d_in[1];
    float* out = (float*)d_out;
    unsigned* Y = (unsigned*)d_ws;      // 16 MB fp16, column-blocked

    rowwaveK1<<<DIM / 4, 256, 0, stream>>>(X, Y, wt);
    int wc = (out_size >= 2 * DIM * DIM) ? 1 : 0;
    colfused<<<DIM / 8, 1024, 0, stream>>>(Y, out, wt, wc);
}

// Round 15
// 42.715 us; speedup vs baseline: 1.0174x; 1.0174x over previous
//
#include <hip/hip_runtime.h>
#include <hip/hip_fp16.h>

// O = U X U^H, U = kron of 11 single-qubit SU(2) gates (2048^2 complex64).
// Reordered as O = U * (X * U^H). Two kernels (round-13 structure, best
// verified 35.3us; round-14's shfl experiment regressed and is reverted):
//   K1 rowpassK1: Y = X U^H (row transform, conj gates). 1 row per
//      128-thread block (2048 blocks), 3 reg phases (j bits 7-10|3-6|0-2),
//      fp32 split-plane LDS + swz. Y fp16 COLUMN-BLOCKED [jblk][row][jin].
//   K2 colfused: full 11-stage column transform, 8-col strip per block,
//      1024 thr, 16 elems/thread, 3 phases, packed half2 LDS (72 KB),
//      XCD-aware strip swizzle.
// THIS ROUND: + nontemporal hints on X loads (read once) and Out stores
// (never re-read) to preserve L2 for the Y intermediate. Nothing else.
// Butterflies: VOP3P packed fp32 (v_pk_fma_f32 + op_sel Re/Im swap, signs
// baked into gate constants). Traffic ~64 MB.

#define DIM 2048
#define NQ 11

typedef float v2f __attribute__((ext_vector_type(2)));

__device__ __forceinline__ int swz(int j) { return j ^ ((j >> 5) & 31); }

__device__ __forceinline__ float2 cmul(float2 a, float2 b) {
    return make_float2(a.x * b.x - a.y * b.y, a.x * b.y + a.y * b.x);
}

// ---- VOP3P packed helpers -------------------------------------------------
__device__ __forceinline__ v2f pkmul_swap(v2f s, v2f g) {
    v2f d;
    asm("v_pk_mul_f32 %0, %1, %2 op_sel:[1,0] op_sel_hi:[0,1]"
        : "=v"(d) : "v"(s), "v"(g));
    return d;
}
__device__ __forceinline__ v2f pkfma(v2f s0, v2f s1, v2f c) {
    v2f d;
    asm("v_pk_fma_f32 %0, %1, %2, %3" : "=v"(d) : "v"(s0), "v"(s1), "v"(c));
    return d;
}
__device__ __forceinline__ v2f pkfma_swap(v2f s0, v2f s1, v2f c) {
    v2f d;
    asm("v_pk_fma_f32 %0, %1, %2, %3 op_sel:[1,0,0] op_sel_hi:[0,1,1]"
        : "=v"(d) : "v"(s0), "v"(s1), "v"(c));
    return d;
}

struct PkGate {
    v2f x00, y00, x01, y01, x10, y10, x11, y11;
};

// Composite gate g = Rz @ Ry @ Rx for qubit q; conj!=0 -> conjugate entries.
__device__ __forceinline__ void make_gate(const float* __restrict__ w, int q,
                                          int conj, float2* out4) {
    const float WM = 0.632455532033675866f;  // sqrt(2/5)
    float hx = 0.5f * WM * w[q * 3 + 0];
    float hy = 0.5f * WM * w[q * 3 + 1];
    float hz = 0.5f * WM * w[q * 3 + 2];
    float cx, sx, cy, sy, cz, sz;
    sincosf(hx, &sx, &cx);
    sincosf(hy, &sy, &cy);
    sincosf(hz, &sz, &cz);
    float2 m00 = make_float2(cy * cx,  sy * sx);
    float2 m01 = make_float2(-sy * cx, -cy * sx);
    float2 m10 = make_float2(sy * cx,  -cy * sx);
    float2 m11 = make_float2(cy * cx,  -sy * sx);
    float2 ez  = make_float2(cz, -sz);
    float2 ezc = make_float2(cz,  sz);
    float2 g00 = cmul(ez, m00);
    float2 g01 = cmul(ez, m01);
    float2 g10 = cmul(ezc, m10);
    float2 g11 = cmul(ezc, m11);
    float sgn = conj ? -1.f : 1.f;
    out4[0] = make_float2(g00.x, sgn * g00.y);
    out4[1] = make_float2(g01.x, sgn * g01.y);
    out4[2] = make_float2(g10.x, sgn * g10.y);
    out4[3] = make_float2(g11.x, sgn * g11.y);
}

__device__ __forceinline__ void build_pk_gates(const float* __restrict__ wt,
                                               int t, int conj,
                                               v2f (*gsh)[8]) {
    if (t < NQ) {
        float2 e[4];
        make_gate(wt, t, conj, e);
#pragma unroll
        for (int k = 0; k < 4; ++k) {
            v2f px = {e[k].x, e[k].x};
            v2f py = {-e[k].y, e[k].y};
            gsh[t][2 * k + 0] = px;
            gsh[t][2 * k + 1] = py;
        }
    }
}

__device__ __forceinline__ void load_pkgate(const v2f (*gsh)[8], int q,
                                            PkGate& G) {
    G.x00 = gsh[q][0]; G.y00 = gsh[q][1];
    G.x01 = gsh[q][2]; G.y01 = gsh[q][3];
    G.x10 = gsh[q][4]; G.y10 = gsh[q][5];
    G.x11 = gsh[q][6]; G.y11 = gsh[q][7];
}

// Butterfly: (A,B) <- (E00 A + E01 B, E10 A + E11 B), 8 VOP3P instrs.
__device__ __forceinline__ void bfly(float2& A, float2& B, const PkGate& G) {
    v2f a = __builtin_bit_cast(v2f, A), b = __builtin_bit_cast(v2f, B);
    v2f t;
    t = pkmul_swap(b, G.y01);
    t = pkfma(b, G.x01, t);
    t = pkfma_swap(a, G.y00, t);
    A = __builtin_bit_cast(float2, pkfma(a, G.x00, t));
    t = pkmul_swap(b, G.y11);
    t = pkfma(b, G.x11, t);
    t = pkfma_swap(a, G.y10, t);
    B = __builtin_bit_cast(float2, pkfma(a, G.x10, t));
}

template <int ST>
__device__ __forceinline__ void stage16(float2* v, const PkGate& G) {
#pragma unroll
    for (int m = 0; m < 16; ++m)
        if (!(m & ST)) bfly(v[m], v[m + ST], G);
}

__device__ __forceinline__ unsigned pack_h2(float2 v) {
    __half2 h = __float22half2_rn(v);
    return *reinterpret_cast<unsigned*>(&h);
}
__device__ __forceinline__ float2 unpack_h2(unsigned u) {
    __half2 h = *reinterpret_cast<__half2*>(&u);
    return __half22float2(h);
}

// ---------------- K1: Y = X U^H (row transform, 1 row/block) ---------------
// 128 threads, 2048 blocks. fp32 split-plane LDS + swz (2-way banks).
// Y layout: column-blocked fp16, Y[jblk][row][jin], jblk=j>>3, jin=j&7.
__global__ __launch_bounds__(128, 2) void rowpassK1(
    const float* __restrict__ X, unsigned* __restrict__ Y,
    const float* __restrict__ wt) {
    __shared__ float pRe[DIM];
    __shared__ float pIm[DIM];
    __shared__ v2f gsh[NQ][8];
    int u = threadIdx.x;                // u = j bits 0-6
    build_pk_gates(wt, u, 1, gsh);      // conjugated gates
    __syncthreads();

    int row = blockIdx.x;
    const float* xrow = X + (size_t)row * DIM;

    // Phase A: j = u + 128m (bits 7-10 -> qubits 3,2,1,0). X real.
    // Nontemporal: X is read exactly once across the whole pipeline.
    float xr[16];
#pragma unroll
    for (int m = 0; m < 16; ++m)
        xr[m] = __builtin_nontemporal_load(&xrow[u + (m << 7)]);

    // real-input first stage (j bit 7, qubit 3), scalar form
    float e00x = gsh[3][0][0], e00y = gsh[3][1][1];
    float e01x = gsh[3][2][0], e01y = gsh[3][3][1];
    float e10x = gsh[3][4][0], e10y = gsh[3][5][1];
    float e11x = gsh[3][6][0], e11y = gsh[3][7][1];
    float2 v[16];
#pragma unroll
    for (int m = 0; m < 16; m += 2) {
        float a = xr[m], b = xr[m + 1];
        v[m]     = make_float2(e00x * a + e01x * b, e00y * a + e01y * b);
        v[m + 1] = make_float2(e10x * a + e11x * b, e10y * a + e11y * b);
    }
    PkGate G;
    load_pkgate(gsh, 2, G); stage16<2>(v, G);   // bit 8
    load_pkgate(gsh, 1, G); stage16<4>(v, G);   // bit 9
    load_pkgate(gsh, 0, G); stage16<8>(v, G);   // bit 10

#pragma unroll
    for (int m = 0; m < 16; ++m) {
        int a = swz(u + (m << 7));
        pRe[a] = v[m].x; pIm[a] = v[m].y;
    }
    __syncthreads();

    // Phase M: j = (u&7) + 8m + 128*(u>>3) (bits 3-6 -> qubits 7,6,5,4).
    int uLo = u & 7, uHi = u >> 3;
#pragma unroll
    for (int m = 0; m < 16; ++m) {
        int a = swz(uLo + (m << 3) + (uHi << 7));
        v[m] = make_float2(pRe[a], pIm[a]);
    }
    load_pkgate(gsh, 7, G); stage16<1>(v, G);
    load_pkgate(gsh, 6, G); stage16<2>(v, G);
    load_pkgate(gsh, 5, G); stage16<4>(v, G);
    load_pkgate(gsh, 4, G); stage16<8>(v, G);
#pragma unroll
    for (int m = 0; m < 16; ++m) {
        int a = swz(uLo + (m << 3) + (uHi << 7));
        pRe[a] = v[m].x; pIm[a] = v[m].y;
    }
    __syncthreads();

    // Phase F: j = m + 16u (bits 0-2 -> qubits 10,9,8).
#pragma unroll
    for (int m = 0; m < 16; ++m) {
        int a = swz(m + (u << 4));
        v[m] = make_float2(pRe[a], pIm[a]);
    }
    load_pkgate(gsh, 10, G); stage16<1>(v, G);
    load_pkgate(gsh, 9, G);  stage16<2>(v, G);
    load_pkgate(gsh, 8, G);  stage16<4>(v, G);

    // Store fp16 column-blocked: j = 16u+e -> jblk = 2u + (e>>3), jin = e&7.
    // (Cached stores: Y is re-read by K2.)
    unsigned* yp = Y + (size_t)(2 * u) * (DIM * 8) + (size_t)row * 8;
    uint4 pk0, pk1;
    pk0.x = pack_h2(v[0]); pk0.y = pack_h2(v[1]);
    pk0.z = pack_h2(v[2]); pk0.w = pack_h2(v[3]);
    pk1.x = pack_h2(v[4]); pk1.y = pack_h2(v[5]);
    pk1.z = pack_h2(v[6]); pk1.w = pack_h2(v[7]);
    *reinterpret_cast<uint4*>(yp) = pk0;
    *reinterpret_cast<uint4*>(yp + 4) = pk1;
    unsigned* yp2 = yp + DIM * 8;       // jblk = 2u+1
    pk0.x = pack_h2(v[8]);  pk0.y = pack_h2(v[9]);
    pk0.z = pack_h2(v[10]); pk0.w = pack_h2(v[11]);
    pk1.x = pack_h2(v[12]); pk1.y = pack_h2(v[13]);
    pk1.z = pack_h2(v[14]); pk1.w = pack_h2(v[15]);
    *reinterpret_cast<uint4*>(yp2) = pk0;
    *reinterpret_cast<uint4*>(yp2 + 4) = pk1;
}

// -------- K2: full column transform (row bits 0-10), 8-col strip -----------
// 1024 threads, 16 elems/thread. Phases: A bits 7-10 | M bits 3-6 | F 0-2.
// LDS: packed half2 (u32), word = r*9 + c (pad-9, <=4-way banks). 72 KB ->
// 2 resident blocks/CU. XCD-aware strip swizzle.
__global__ __launch_bounds__(1024, 4) void colfused(
    const unsigned* __restrict__ Y, float* __restrict__ Out,
    const float* __restrict__ wt, int writeComplex) {
    __shared__ unsigned pk[DIM * 9];
    __shared__ v2f gsh[NQ][8];
    int t = threadIdx.x;
    build_pk_gates(wt, t, 0, gsh);
    __syncthreads();

    // XCD swizzle (8 XCDs, 256 blocks): strips 32k..32k+31 share XCD k.
    int strip = ((blockIdx.x & 7) << 5) + (blockIdx.x >> 3);

    int c = t & 7, u = t >> 3;          // u in 0..127
    const unsigned* yb = Y + (size_t)strip * (DIM * 8);

    // Phase A: r = u + 128m (bits 7-10 -> qubits 3,2,1,0).
    float2 v[16];
    PkGate G;
#pragma unroll
    for (int m = 0; m < 16; ++m)
        v[m] = unpack_h2(yb[(u + (m << 7)) * 8 + c]);

    load_pkgate(gsh, 3, G); stage16<1>(v, G);   // bit 7
    load_pkgate(gsh, 2, G); stage16<2>(v, G);   // bit 8
    load_pkgate(gsh, 1, G); stage16<4>(v, G);   // bit 9
    load_pkgate(gsh, 0, G); stage16<8>(v, G);   // bit 10

#pragma unroll
    for (int m = 0; m < 16; ++m)
        pk[(u + (m << 7)) * 9 + c] = pack_h2(v[m]);
    __syncthreads();

    // Phase M: r = (u&7) + 8m + 128*(u>>3) (bits 3-6 -> qubits 7,6,5,4).
    int uLo = u & 7, uHi = u >> 3;
#pragma unroll
    for (int m = 0; m < 16; ++m)
        v[m] = unpack_h2(pk[(uLo + (m << 3) + (uHi << 7)) * 9 + c]);
    load_pkgate(gsh, 7, G); stage16<1>(v, G);
    load_pkgate(gsh, 6, G); stage16<2>(v, G);
    load_pkgate(gsh, 5, G); stage16<4>(v, G);
    load_pkgate(gsh, 4, G); stage16<8>(v, G);
#pragma unroll
    for (int m = 0; m < 16; ++m)
        pk[(uLo + (m << 3) + (uHi << 7)) * 9 + c] = pack_h2(v[m]);
    __syncthreads();

    // Phase F: r = m + 16u (bits 0-2 -> qubits 10,9,8).
#pragma unroll
    for (int m = 0; m < 16; ++m)
        v[m] = unpack_h2(pk[(m + (u << 4)) * 9 + c]);
    load_pkgate(gsh, 10, G); stage16<1>(v, G);
    load_pkgate(gsh, 9, G);  stage16<2>(v, G);
    load_pkgate(gsh, 8, G);  stage16<4>(v, G);

    // Write: thread holds rows r = 16u..16u+15 of column j = strip*8 + c.
    // Nontemporal: Out is never re-read.
    int j = strip * 8 + c;
    if (!writeComplex) {
#pragma unroll
        for (int m = 0; m < 16; ++m)
            __builtin_nontemporal_store(v[m].x,
                                        &Out[(size_t)(m + (u << 4)) * DIM + j]);
    } else {
        float2* o2 = (float2*)Out;
#pragma unroll
        for (int m = 0; m < 16; ++m)
            o2[(size_t)(m + (u << 4)) * DIM + j] = v[m];
    }
}

extern "C" void kernel_launch(void* const* d_in, const int* in_sizes, int n_in,
                              void* d_out, int out_size, void* d_ws,
                              size_t ws_size, hipStream_t stream) {
    const float* X = (const float*)d_in[0];
    const float* wt = (const float*)d_in[1];
    float* out = (float*)d_out;
    unsigned* Y = (unsigned*)d_ws;      // 16 MB fp16, column-blocked

    rowpassK1<<<DIM, 128, 0, stream>>>(X, Y, wt);
    int wc = (out_size >= 2 * DIM * DIM) ? 1 : 0;
    colfused<<<DIM / 8, 1024, 0, stream>>>(Y, out, wt, wc);
}

// Round 16
// 35.550 us; speedup vs baseline: 1.2224x; 1.2016x over previous
//
#include <hip/hip_runtime.h>
#include <hip/hip_fp16.h>

// O = U X U^H, U = kron of 11 single-qubit SU(2) gates (2048^2 complex64).
// Reordered as O = U * (X * U^H). Two kernels. ROUND-13 VERBATIM REVERT
// (best verified: 35.3 us). Round-14 (shfl butterflies) and round-15
// (nontemporal hints) both regressed: shfl costs 2 cross-lane ops per
// element per stage vs LDS's amortized cost, and nt hints defeat the L3
// residency of the 48 MB working set across graph replays.
//   K1 rowpassK1: Y = X U^H (row transform, conj gates). 1 row per
//      128-thread block (2048 blocks), 3 reg phases (j bits 7-10|3-6|0-2),
//      fp32 split-plane LDS + swz (2-way banks). Y fp16 COLUMN-BLOCKED
//      [jblk=j>>3][row][jin=j&7] so K2's reads coalesce.
//   K2 colfused: full 11-stage column transform, 8-col strip per block,
//      1024 thr, 16 elems/thread, 3 phases, packed half2 LDS (72 KB,
//      2 blocks/CU), XCD-aware strip swizzle.
// Butterflies: VOP3P packed fp32 (v_pk_fma_f32 + op_sel Re/Im swap, signs
// baked into gate constants) - 8 instrs/bfly. Traffic ~64 MB.

#define DIM 2048
#define NQ 11

typedef float v2f __attribute__((ext_vector_type(2)));

__device__ __forceinline__ int swz(int j) { return j ^ ((j >> 5) & 31); }

__device__ __forceinline__ float2 cmul(float2 a, float2 b) {
    return make_float2(a.x * b.x - a.y * b.y, a.x * b.y + a.y * b.x);
}

// ---- VOP3P packed helpers -------------------------------------------------
__device__ __forceinline__ v2f pkmul_swap(v2f s, v2f g) {
    v2f d;
    asm("v_pk_mul_f32 %0, %1, %2 op_sel:[1,0] op_sel_hi:[0,1]"
        : "=v"(d) : "v"(s), "v"(g));
    return d;
}
__device__ __forceinline__ v2f pkfma(v2f s0, v2f s1, v2f c) {
    v2f d;
    asm("v_pk_fma_f32 %0, %1, %2, %3" : "=v"(d) : "v"(s0), "v"(s1), "v"(c));
    return d;
}
__device__ __forceinline__ v2f pkfma_swap(v2f s0, v2f s1, v2f c) {
    v2f d;
    asm("v_pk_fma_f32 %0, %1, %2, %3 op_sel:[1,0,0] op_sel_hi:[0,1,1]"
        : "=v"(d) : "v"(s0), "v"(s1), "v"(c));
    return d;
}

struct PkGate {
    v2f x00, y00, x01, y01, x10, y10, x11, y11;
};

// Composite gate g = Rz @ Ry @ Rx for qubit q; conj!=0 -> conjugate entries.
__device__ __forceinline__ void make_gate(const float* __restrict__ w, int q,
                                          int conj, float2* out4) {
    const float WM = 0.632455532033675866f;  // sqrt(2/5)
    float hx = 0.5f * WM * w[q * 3 + 0];
    float hy = 0.5f * WM * w[q * 3 + 1];
    float hz = 0.5f * WM * w[q * 3 + 2];
    float cx, sx, cy, sy, cz, sz;
    sincosf(hx, &sx, &cx);
    sincosf(hy, &sy, &cy);
    sincosf(hz, &sz, &cz);
    float2 m00 = make_float2(cy * cx,  sy * sx);
    float2 m01 = make_float2(-sy * cx, -cy * sx);
    float2 m10 = make_float2(sy * cx,  -cy * sx);
    float2 m11 = make_float2(cy * cx,  -sy * sx);
    float2 ez  = make_float2(cz, -sz);
    float2 ezc = make_float2(cz,  sz);
    float2 g00 = cmul(ez, m00);
    float2 g01 = cmul(ez, m01);
    float2 g10 = cmul(ezc, m10);
    float2 g11 = cmul(ezc, m11);
    float sgn = conj ? -1.f : 1.f;
    out4[0] = make_float2(g00.x, sgn * g00.y);
    out4[1] = make_float2(g01.x, sgn * g01.y);
    out4[2] = make_float2(g10.x, sgn * g10.y);
    out4[3] = make_float2(g11.x, sgn * g11.y);
}

__device__ __forceinline__ void build_pk_gates(const float* __restrict__ wt,
                                               int t, int conj,
                                               v2f (*gsh)[8]) {
    if (t < NQ) {
        float2 e[4];
        make_gate(wt, t, conj, e);
#pragma unroll
        for (int k = 0; k < 4; ++k) {
            v2f px = {e[k].x, e[k].x};
            v2f py = {-e[k].y, e[k].y};
            gsh[t][2 * k + 0] = px;
            gsh[t][2 * k + 1] = py;
        }
    }
}

__device__ __forceinline__ void load_pkgate(const v2f (*gsh)[8], int q,
                                            PkGate& G) {
    G.x00 = gsh[q][0]; G.y00 = gsh[q][1];
    G.x01 = gsh[q][2]; G.y01 = gsh[q][3];
    G.x10 = gsh[q][4]; G.y10 = gsh[q][5];
    G.x11 = gsh[q][6]; G.y11 = gsh[q][7];
}

// Butterfly: (A,B) <- (E00 A + E01 B, E10 A + E11 B), 8 VOP3P instrs.
__device__ __forceinline__ void bfly(float2& A, float2& B, const PkGate& G) {
    v2f a = __builtin_bit_cast(v2f, A), b = __builtin_bit_cast(v2f, B);
    v2f t;
    t = pkmul_swap(b, G.y01);
    t = pkfma(b, G.x01, t);
    t = pkfma_swap(a, G.y00, t);
    A = __builtin_bit_cast(float2, pkfma(a, G.x00, t));
    t = pkmul_swap(b, G.y11);
    t = pkfma(b, G.x11, t);
    t = pkfma_swap(a, G.y10, t);
    B = __builtin_bit_cast(float2, pkfma(a, G.x10, t));
}

template <int ST>
__device__ __forceinline__ void stage16(float2* v, const PkGate& G) {
#pragma unroll
    for (int m = 0; m < 16; ++m)
        if (!(m & ST)) bfly(v[m], v[m + ST], G);
}

__device__ __forceinline__ unsigned pack_h2(float2 v) {
    __half2 h = __float22half2_rn(v);
    return *reinterpret_cast<unsigned*>(&h);
}
__device__ __forceinline__ float2 unpack_h2(unsigned u) {
    __half2 h = *reinterpret_cast<__half2*>(&u);
    return __half22float2(h);
}

// ---------------- K1: Y = X U^H (row transform, 1 row/block) ---------------
// 128 threads, 2048 blocks. fp32 split-plane LDS + swz (2-way banks).
// Y layout: column-blocked fp16, Y[jblk][row][jin], jblk=j>>3, jin=j&7.
__global__ __launch_bounds__(128, 2) void rowpassK1(
    const float* __restrict__ X, unsigned* __restrict__ Y,
    const float* __restrict__ wt) {
    __shared__ float pRe[DIM];
    __shared__ float pIm[DIM];
    __shared__ v2f gsh[NQ][8];
    int u = threadIdx.x;                // u = j bits 0-6
    build_pk_gates(wt, u, 1, gsh);      // conjugated gates
    __syncthreads();

    int row = blockIdx.x;
    const float* xrow = X + (size_t)row * DIM;

    // Phase A: j = u + 128m (bits 7-10 -> qubits 3,2,1,0). X real.
    float xr[16];
#pragma unroll
    for (int m = 0; m < 16; ++m) xr[m] = xrow[u + (m << 7)];

    // real-input first stage (j bit 7, qubit 3), scalar form
    float e00x = gsh[3][0][0], e00y = gsh[3][1][1];
    float e01x = gsh[3][2][0], e01y = gsh[3][3][1];
    float e10x = gsh[3][4][0], e10y = gsh[3][5][1];
    float e11x = gsh[3][6][0], e11y = gsh[3][7][1];
    float2 v[16];
#pragma unroll
    for (int m = 0; m < 16; m += 2) {
        float a = xr[m], b = xr[m + 1];
        v[m]     = make_float2(e00x * a + e01x * b, e00y * a + e01y * b);
        v[m + 1] = make_float2(e10x * a + e11x * b, e10y * a + e11y * b);
    }
    PkGate G;
    load_pkgate(gsh, 2, G); stage16<2>(v, G);   // bit 8
    load_pkgate(gsh, 1, G); stage16<4>(v, G);   // bit 9
    load_pkgate(gsh, 0, G); stage16<8>(v, G);   // bit 10

#pragma unroll
    for (int m = 0; m < 16; ++m) {
        int a = swz(u + (m << 7));
        pRe[a] = v[m].x; pIm[a] = v[m].y;
    }
    __syncthreads();

    // Phase M: j = (u&7) + 8m + 128*(u>>3) (bits 3-6 -> qubits 7,6,5,4).
    int uLo = u & 7, uHi = u >> 3;
#pragma unroll
    for (int m = 0; m < 16; ++m) {
        int a = swz(uLo + (m << 3) + (uHi << 7));
        v[m] = make_float2(pRe[a], pIm[a]);
    }
    load_pkgate(gsh, 7, G); stage16<1>(v, G);
    load_pkgate(gsh, 6, G); stage16<2>(v, G);
    load_pkgate(gsh, 5, G); stage16<4>(v, G);
    load_pkgate(gsh, 4, G); stage16<8>(v, G);
#pragma unroll
    for (int m = 0; m < 16; ++m) {
        int a = swz(uLo + (m << 3) + (uHi << 7));
        pRe[a] = v[m].x; pIm[a] = v[m].y;
    }
    __syncthreads();

    // Phase F: j = m + 16u (bits 0-2 -> qubits 10,9,8).
#pragma unroll
    for (int m = 0; m < 16; ++m) {
        int a = swz(m + (u << 4));
        v[m] = make_float2(pRe[a], pIm[a]);
    }
    load_pkgate(gsh, 10, G); stage16<1>(v, G);
    load_pkgate(gsh, 9, G);  stage16<2>(v, G);
    load_pkgate(gsh, 8, G);  stage16<4>(v, G);

    // Store fp16 column-blocked: j = 16u+e -> jblk = 2u + (e>>3), jin = e&7.
    unsigned* yp = Y + (size_t)(2 * u) * (DIM * 8) + (size_t)row * 8;
    uint4 pk0, pk1;
    pk0.x = pack_h2(v[0]); pk0.y = pack_h2(v[1]);
    pk0.z = pack_h2(v[2]); pk0.w = pack_h2(v[3]);
    pk1.x = pack_h2(v[4]); pk1.y = pack_h2(v[5]);
    pk1.z = pack_h2(v[6]); pk1.w = pack_h2(v[7]);
    *reinterpret_cast<uint4*>(yp) = pk0;
    *reinterpret_cast<uint4*>(yp + 4) = pk1;
    unsigned* yp2 = yp + DIM * 8;       // jblk = 2u+1
    pk0.x = pack_h2(v[8]);  pk0.y = pack_h2(v[9]);
    pk0.z = pack_h2(v[10]); pk0.w = pack_h2(v[11]);
    pk1.x = pack_h2(v[12]); pk1.y = pack_h2(v[13]);
    pk1.z = pack_h2(v[14]); pk1.w = pack_h2(v[15]);
    *reinterpret_cast<uint4*>(yp2) = pk0;
    *reinterpret_cast<uint4*>(yp2 + 4) = pk1;
}

// -------- K2: full column transform (row bits 0-10), 8-col strip -----------
// 1024 threads, 16 elems/thread. Phases: A bits 7-10 | M bits 3-6 | F 0-2.
// LDS: packed half2 (u32), word = r*9 + c (pad-9, <=4-way banks). 72 KB ->
// 2 resident blocks/CU. XCD-aware strip swizzle.
__global__ __launch_bounds__(1024, 4) void colfused(
    const unsigned* __restrict__ Y, float* __restrict__ Out,
    const float* __restrict__ wt, int writeComplex) {
    __shared__ unsigned pk[DIM * 9];
    __shared__ v2f gsh[NQ][8];
    int t = threadIdx.x;
    build_pk_gates(wt, t, 0, gsh);
    __syncthreads();

    // XCD swizzle (8 XCDs, 256 blocks): strips 32k..32k+31 share XCD k.
    int strip = ((blockIdx.x & 7) << 5) + (blockIdx.x >> 3);

    int c = t & 7, u = t >> 3;          // u in 0..127
    const unsigned* yb = Y + (size_t)strip * (DIM * 8);

    // Phase A: r = u + 128m (bits 7-10 -> qubits 3,2,1,0).
    float2 v[16];
    PkGate G;
#pragma unroll
    for (int m = 0; m < 16; ++m)
        v[m] = unpack_h2(yb[(u + (m << 7)) * 8 + c]);

    load_pkgate(gsh, 3, G); stage16<1>(v, G);   // bit 7
    load_pkgate(gsh, 2, G); stage16<2>(v, G);   // bit 8
    load_pkgate(gsh, 1, G); stage16<4>(v, G);   // bit 9
    load_pkgate(gsh, 0, G); stage16<8>(v, G);   // bit 10

#pragma unroll
    for (int m = 0; m < 16; ++m)
        pk[(u + (m << 7)) * 9 + c] = pack_h2(v[m]);
    __syncthreads();

    // Phase M: r = (u&7) + 8m + 128*(u>>3) (bits 3-6 -> qubits 7,6,5,4).
    int uLo = u & 7, uHi = u >> 3;
#pragma unroll
    for (int m = 0; m < 16; ++m)
        v[m] = unpack_h2(pk[(uLo + (m << 3) + (uHi << 7)) * 9 + c]);
    load_pkgate(gsh, 7, G); stage16<1>(v, G);
    load_pkgate(gsh, 6, G); stage16<2>(v, G);
    load_pkgate(gsh, 5, G); stage16<4>(v, G);
    load_pkgate(gsh, 4, G); stage16<8>(v, G);
#pragma unroll
    for (int m = 0; m < 16; ++m)
        pk[(uLo + (m << 3) + (uHi << 7)) * 9 + c] = pack_h2(v[m]);
    __syncthreads();

    // Phase F: r = m + 16u (bits 0-2 -> qubits 10,9,8).
#pragma unroll
    for (int m = 0; m < 16; ++m)
        v[m] = unpack_h2(pk[(m + (u << 4)) * 9 + c]);
    load_pkgate(gsh, 10, G); stage16<1>(v, G);
    load_pkgate(gsh, 9, G);  stage16<2>(v, G);
    load_pkgate(gsh, 8, G);  stage16<4>(v, G);

    // Write: thread holds rows r = 16u..16u+15 of column j = strip*8 + c.
    int j = strip * 8 + c;
    if (!writeComplex) {
#pragma unroll
        for (int m = 0; m < 16; ++m)
            Out[(size_t)(m + (u << 4)) * DIM + j] = v[m].x;
    } else {
        float2* o2 = (float2*)Out;
#pragma unroll
        for (int m = 0; m < 16; ++m)
            o2[(size_t)(m + (u << 4)) * DIM + j] = v[m];
    }
}

extern "C" void kernel_launch(void* const* d_in, const int* in_sizes, int n_in,
                              void* d_out, int out_size, void* d_ws,
                              size_t ws_size, hipStream_t stream) {
    const float* X = (const float*)d_in[0];
    const float* wt = (const float*)d_in[1];
    float* out = (float*)d_out;
    unsigned* Y = (unsigned*)d_ws;      // 16 MB fp16, column-blocked

    rowpassK1<<<DIM, 128, 0, stream>>>(X, Y, wt);
    int wc = (out_size >= 2 * DIM * DIM) ? 1 : 0;
    colfused<<<DIM / 8, 1024, 0, stream>>>(Y, out, wt, wc);
}